// Round 4
// baseline (1557.786 us; speedup 1.0000x reference)
//
#include <hip/hip_runtime.h>
#include <hip/hip_fp16.h>

// DeformConv2d: B=16, Cin=64, Cout=64, H=W=64, K=3, stride=1, pad=1, dil=1
// Round 4 = Round 3 intent, fixed:
//  - geometry phase now covers all 9*32=288 entries (tap 8 was uninitialized
//    -> garbage addresses -> OOB gather -> abort)
//  - __align__(16) on LDS arrays used with b128 ds ops
// Design: 32-px blocks (grid 2048 -> 8 blocks/CU), slim gather records
// (clamped base addr + validity-folded weights), shfl offset-conv reduction.

#define HDIM 64
#define WDIM 64
#define KOFF 18
#define CPAD 40          // padded k-stride (halfs): 80B rows
#define PXB 32           // pixels per block
#define GSTR 33          // geometry stride (records) to break bank alignment

typedef _Float16 half8 __attribute__((ext_vector_type(8)));
typedef float floatx4 __attribute__((ext_vector_type(4)));

// ---------------------------------------------------------------------------
// convert w_dcn [64co][576k] fp32 -> f16 (same layout) in ws
__global__ void cvt_w(const float* __restrict__ w_dcn, _Float16* __restrict__ w2) {
    int e = blockIdx.x * 256 + threadIdx.x;
    if (e < 576 * 64) w2[e] = (_Float16)w_dcn[e];
}

// ---------------------------------------------------------------------------
__launch_bounds__(256, 8)
__global__ void dcn_main(const float* __restrict__ x,
                         const float* __restrict__ w_off,
                         const float* __restrict__ b_off,
                         const float* __restrict__ w_dcn,
                         const _Float16* __restrict__ w2,
                         const float* __restrict__ b_dcn,
                         float* __restrict__ out,
                         int use_wt) {
    const int bx   = blockIdx.x;        // 0..2047
    const int b    = bx >> 7;           // batch
    const int ho   = (bx >> 1) & 63;    // output row
    const int half = bx & 1;            // which 32-px half of the row
    const int t    = threadIdx.x;
    const int lane = t & 63;
    const int wid  = t >> 6;            // wave id 0..3

    __shared__ __align__(16) float    offlds[KOFF * PXB];   // 2304 B
    __shared__ __align__(16) unsigned gmeta[9 * GSTR];      // 1188 B
    __shared__ __align__(16) float4   gwts[9 * GSTR];       // 4752 B
    __shared__ __align__(16) _Float16 colsT[PXB * CPAD];    // 2560 B [32px][40k]
    __shared__ __align__(16) _Float16 wlds[64 * CPAD];      // 5120 B [64co][40k]
    // total ~15.9 KB -> LDS allows 10 blocks/CU; grid gives 8.

    const float* xb = x + (size_t)b * 64 * (HDIM * WDIM);

    // ---------------- phase -1: offset conv (18ch x 32px), shfl reduce -----
    {
        const int px = t >> 3;           // 0..31
        const int c8 = t & 7;            // cin chunk (8 each)
        const int gx = half * PXB + px;  // global wo
        const int cb = c8 * 8;
        float acc[KOFF];
#pragma unroll
        for (int i = 0; i < KOFF; ++i) acc[i] = 0.f;

        for (int ci = 0; ci < 8; ++ci) {
            const float* xc = xb + (size_t)(cb + ci) * (HDIM * WDIM);
#pragma unroll
            for (int ky = 0; ky < 3; ++ky) {
                int y = ho + ky - 1;
                bool yok = ((unsigned)y < (unsigned)HDIM);
#pragma unroll
                for (int kx = 0; kx < 3; ++kx) {
                    int xcol = gx + kx - 1;
                    bool ok = yok && ((unsigned)xcol < (unsigned)WDIM);
                    float xv = ok ? xc[y * WDIM + xcol] : 0.f;
#pragma unroll
                    for (int co = 0; co < KOFF; ++co)
                        acc[co] += xv * w_off[co * 576 + (cb + ci) * 9 + ky * 3 + kx];
                }
            }
        }
        // butterfly sum over the 8 cin-chunks (lanes differing in bits 0..2)
#pragma unroll
        for (int co = 0; co < KOFF; ++co) {
            float v = acc[co];
            v += __shfl_xor(v, 1);
            v += __shfl_xor(v, 2);
            v += __shfl_xor(v, 4);
            if (c8 == 0) offlds[co * PXB + px] = v + b_off[co];
        }
    }
    __syncthreads();

    // ---------------- phase 0: clamped-address geometry (288 entries) ------
    for (int e = t; e < 9 * PXB; e += 256) {
        int tap = e >> 5;                // 0..8
        int px  = e & 31;
        float offy = offlds[(2 * tap) * PXB + px];
        float offx = offlds[(2 * tap + 1) * PXB + px];
        float py  = offy + (float)(tap / 3) + (float)(ho - 1);
        float pxf = offx + (float)(tap % 3) + (float)(half * PXB + px - 1);
        float fy = floorf(py), fx = floorf(pxf);
        int y0 = (int)fy, x0 = (int)fx;
        float wy1 = py - fy, wx1 = pxf - fx;
        float wy0 = 1.f - wy1, wx0 = 1.f - wx1;
        bool y0ok = ((unsigned)y0 < (unsigned)HDIM);
        bool x0ok = ((unsigned)x0 < (unsigned)WDIM);
        bool y1ok = ((unsigned)(y0 + 1) < (unsigned)HDIM);
        bool x1ok = ((unsigned)(x0 + 1) < (unsigned)WDIM);
        float4 w;
        w.x = (y0ok && x0ok) ? wy0 * wx0 : 0.f;
        w.y = (y0ok && x1ok) ? wy0 * wx1 : 0.f;
        w.z = (y1ok && x0ok) ? wy1 * wx0 : 0.f;
        w.w = (y1ok && x1ok) ? wy1 * wx1 : 0.f;
        int yc0 = min(max(y0, 0), HDIM - 1);
        int xc0 = min(max(x0, 0), WDIM - 1);
        int yc1 = min(max(y0 + 1, 0), HDIM - 1);
        int xc1 = min(max(x0 + 1, 0), WDIM - 1);
        unsigned base = (unsigned)(yc0 * WDIM + xc0);      // <= 4095
        unsigned dx   = (unsigned)(xc1 - xc0);             // 0 or 1
        unsigned dy   = (unsigned)(yc1 - yc0);             // 0 or 1
        gmeta[tap * GSTR + px] = base | (dx << 12) | (dy << 13);
        gwts[tap * GSTR + px]  = w;
    }
    __syncthreads();

    // ---------------- main loop: 18 k-groups of 32 -------------------------
    const int kl = t & 31;              // k within group (gather role)
    const int p0 = (t >> 5) * 4;        // 4-pixel strip (gather role)
    const int wco = t >> 2;             // staging role: cout
    const int wk  = (t & 3) * 8;        // staging role: k offset
    floatx4 acc0 = {0.f, 0.f, 0.f, 0.f};
    floatx4 acc1 = {0.f, 0.f, 0.f, 0.f};

    for (int kg0 = 0; kg0 < 576; kg0 += 32) {
        // ---- stage weight k-group [64co][32k] -> wlds ----
        if (use_wt) {
            *(half8*)&wlds[wco * CPAD + wk] =
                *(const half8*)&w2[wco * 576 + kg0 + wk];
        } else {
            const float4* ws4 = (const float4*)&w_dcn[wco * 576 + kg0 + wk];
            float4 f0 = ws4[0], f1 = ws4[1];
            half8 wv;
            wv[0] = (_Float16)f0.x; wv[1] = (_Float16)f0.y;
            wv[2] = (_Float16)f0.z; wv[3] = (_Float16)f0.w;
            wv[4] = (_Float16)f1.x; wv[5] = (_Float16)f1.y;
            wv[6] = (_Float16)f1.z; wv[7] = (_Float16)f1.w;
            *(half8*)&wlds[wco * CPAD + wk] = wv;
        }

        // ---- gather: thread owns k = kg0+kl, pixels p0..p0+3 ----
        int k   = kg0 + kl;
        int cin = k / 9;
        int tap = k - cin * 9;
        const float* xc = xb + (size_t)cin * (HDIM * WDIM);
#pragma unroll
        for (int i = 0; i < 4; ++i) {
            int px = p0 + i;
            unsigned m = gmeta[tap * GSTR + px];
            float4 w  = gwts[tap * GSTR + px];
            unsigned base = m & 0xfffu;
            unsigned dx   = (m >> 12) & 1u;
            unsigned dy64 = (m >> 7) & 64u;    // ((m>>13)&1)*64
            float v00 = xc[base];
            float v01 = xc[base + dx];
            float v10 = xc[base + dy64];
            float v11 = xc[base + dy64 + dx];
            float v = v00 * w.x + v01 * w.y + v10 * w.z + v11 * w.w;
            colsT[px * CPAD + kl] = (_Float16)v;
        }
        __syncthreads();

        // ---- MFMA: wave wid -> cout rows [16*wid, 16*wid+16), 2 px tiles --
        half8 afrag = *(const half8*)&wlds[(wid * 16 + (lane & 15)) * CPAD + (lane >> 4) * 8];
        half8 b0 = *(const half8*)&colsT[(lane & 15) * CPAD + (lane >> 4) * 8];
        half8 b1 = *(const half8*)&colsT[(16 + (lane & 15)) * CPAD + (lane >> 4) * 8];
        acc0 = __builtin_amdgcn_mfma_f32_16x16x32_f16(afrag, b0, acc0, 0, 0, 0);
        acc1 = __builtin_amdgcn_mfma_f32_16x16x32_f16(afrag, b1, acc1, 0, 0, 0);
        __syncthreads();
    }

    // ---------------- epilogue: bias + store -------------------------------
    const int col = lane & 15;
    const int r0  = (lane >> 4) * 4;
#pragma unroll
    for (int r = 0; r < 4; ++r) {
        int co = wid * 16 + r0 + r;
        float bias = b_dcn[co];
        size_t o = (((size_t)b * 64 + co) * HDIM + ho) * WDIM + half * PXB;
        out[o + col]      = acc0[r] + bias;
        out[o + 16 + col] = acc1[r] + bias;
    }
}

// ---------------------------------------------------------------------------
extern "C" void kernel_launch(void* const* d_in, const int* in_sizes, int n_in,
                              void* d_out, int out_size, void* d_ws, size_t ws_size,
                              hipStream_t stream) {
    const float* x     = (const float*)d_in[0];
    const float* w_off = (const float*)d_in[1];
    const float* b_off = (const float*)d_in[2];
    const float* w_dcn = (const float*)d_in[3];
    const float* b_dcn = (const float*)d_in[4];
    float* out = (float*)d_out;
    _Float16* w2 = (_Float16*)d_ws;

    int use_wt = (ws_size >= 576 * 64 * sizeof(_Float16)) ? 1 : 0;
    if (use_wt) {
        cvt_w<<<144, 256, 0, stream>>>(w_dcn, w2);
    }
    dcn_main<<<2048, 256, 0, stream>>>(x, w_off, b_off, w_dcn, w2, b_dcn, out,
                                       use_wt);
}

// Round 5
// 1023.955 us; speedup vs baseline: 1.5213x; 1.5213x over previous
//
#include <hip/hip_runtime.h>
#include <hip/hip_fp16.h>

// DeformConv2d: B=16, Cin=64, Cout=64, H=W=64, K=3, stride=1, pad=1, dil=1
// Round 5 = Round 4 with the spill fixed: __launch_bounds__(256,8) capped
// VGPRs at 64 -> 32 and spilled the offset-conv loop to scratch (3.7 GB HBM
// traffic/dispatch, 7x regression). Relax to (256,4): cap 128, compiler
// lands ~44-60 VGPRs -> still 8 waves/SIMD occupancy, no spills.

#define HDIM 64
#define WDIM 64
#define KOFF 18
#define CPAD 40          // padded k-stride (halfs): 80B rows
#define PXB 32           // pixels per block
#define GSTR 33          // geometry stride (records) to break bank alignment

typedef _Float16 half8 __attribute__((ext_vector_type(8)));
typedef float floatx4 __attribute__((ext_vector_type(4)));

// ---------------------------------------------------------------------------
// convert w_dcn [64co][576k] fp32 -> f16 (same layout) in ws
__global__ void cvt_w(const float* __restrict__ w_dcn, _Float16* __restrict__ w2) {
    int e = blockIdx.x * 256 + threadIdx.x;
    if (e < 576 * 64) w2[e] = (_Float16)w_dcn[e];
}

// ---------------------------------------------------------------------------
__launch_bounds__(256, 4)
__global__ void dcn_main(const float* __restrict__ x,
                         const float* __restrict__ w_off,
                         const float* __restrict__ b_off,
                         const float* __restrict__ w_dcn,
                         const _Float16* __restrict__ w2,
                         const float* __restrict__ b_dcn,
                         float* __restrict__ out,
                         int use_wt) {
    const int bx   = blockIdx.x;        // 0..2047
    const int b    = bx >> 7;           // batch
    const int ho   = (bx >> 1) & 63;    // output row
    const int half = bx & 1;            // which 32-px half of the row
    const int t    = threadIdx.x;
    const int lane = t & 63;
    const int wid  = t >> 6;            // wave id 0..3

    __shared__ __align__(16) float    offlds[KOFF * PXB];   // 2304 B
    __shared__ __align__(16) unsigned gmeta[9 * GSTR];      // 1188 B
    __shared__ __align__(16) float4   gwts[9 * GSTR];       // 4752 B
    __shared__ __align__(16) _Float16 colsT[PXB * CPAD];    // 2560 B [32px][40k]
    __shared__ __align__(16) _Float16 wlds[64 * CPAD];      // 5120 B [64co][40k]
    // total ~15.9 KB

    const float* xb = x + (size_t)b * 64 * (HDIM * WDIM);

    // ---------------- phase -1: offset conv (18ch x 32px), shfl reduce -----
    {
        const int px = t >> 3;           // 0..31
        const int c8 = t & 7;            // cin chunk (8 each)
        const int gx = half * PXB + px;  // global wo
        const int cb = c8 * 8;
        float acc[KOFF];
#pragma unroll
        for (int i = 0; i < KOFF; ++i) acc[i] = 0.f;

        for (int ci = 0; ci < 8; ++ci) {
            const float* xc = xb + (size_t)(cb + ci) * (HDIM * WDIM);
#pragma unroll
            for (int ky = 0; ky < 3; ++ky) {
                int y = ho + ky - 1;
                bool yok = ((unsigned)y < (unsigned)HDIM);
#pragma unroll
                for (int kx = 0; kx < 3; ++kx) {
                    int xcol = gx + kx - 1;
                    bool ok = yok && ((unsigned)xcol < (unsigned)WDIM);
                    float xv = ok ? xc[y * WDIM + xcol] : 0.f;
#pragma unroll
                    for (int co = 0; co < KOFF; ++co)
                        acc[co] += xv * w_off[co * 576 + (cb + ci) * 9 + ky * 3 + kx];
                }
            }
        }
        // butterfly sum over the 8 cin-chunks (lanes differing in bits 0..2)
#pragma unroll
        for (int co = 0; co < KOFF; ++co) {
            float v = acc[co];
            v += __shfl_xor(v, 1);
            v += __shfl_xor(v, 2);
            v += __shfl_xor(v, 4);
            if (c8 == 0) offlds[co * PXB + px] = v + b_off[co];
        }
    }
    __syncthreads();

    // ---------------- phase 0: clamped-address geometry (288 entries) ------
    for (int e = t; e < 9 * PXB; e += 256) {
        int tap = e >> 5;                // 0..8
        int px  = e & 31;
        float offy = offlds[(2 * tap) * PXB + px];
        float offx = offlds[(2 * tap + 1) * PXB + px];
        float py  = offy + (float)(tap / 3) + (float)(ho - 1);
        float pxf = offx + (float)(tap % 3) + (float)(half * PXB + px - 1);
        float fy = floorf(py), fx = floorf(pxf);
        int y0 = (int)fy, x0 = (int)fx;
        float wy1 = py - fy, wx1 = pxf - fx;
        float wy0 = 1.f - wy1, wx0 = 1.f - wx1;
        bool y0ok = ((unsigned)y0 < (unsigned)HDIM);
        bool x0ok = ((unsigned)x0 < (unsigned)WDIM);
        bool y1ok = ((unsigned)(y0 + 1) < (unsigned)HDIM);
        bool x1ok = ((unsigned)(x0 + 1) < (unsigned)WDIM);
        float4 w;
        w.x = (y0ok && x0ok) ? wy0 * wx0 : 0.f;
        w.y = (y0ok && x1ok) ? wy0 * wx1 : 0.f;
        w.z = (y1ok && x0ok) ? wy1 * wx0 : 0.f;
        w.w = (y1ok && x1ok) ? wy1 * wx1 : 0.f;
        int yc0 = min(max(y0, 0), HDIM - 1);
        int xc0 = min(max(x0, 0), WDIM - 1);
        int yc1 = min(max(y0 + 1, 0), HDIM - 1);
        int xc1 = min(max(x0 + 1, 0), WDIM - 1);
        unsigned base = (unsigned)(yc0 * WDIM + xc0);      // <= 4095
        unsigned dx   = (unsigned)(xc1 - xc0);             // 0 or 1
        unsigned dy   = (unsigned)(yc1 - yc0);             // 0 or 1
        gmeta[tap * GSTR + px] = base | (dx << 12) | (dy << 13);
        gwts[tap * GSTR + px]  = w;
    }
    __syncthreads();

    // ---------------- main loop: 18 k-groups of 32 -------------------------
    const int kl = t & 31;              // k within group (gather role)
    const int p0 = (t >> 5) * 4;        // 4-pixel strip (gather role)
    const int wco = t >> 2;             // staging role: cout
    const int wk  = (t & 3) * 8;        // staging role: k offset
    floatx4 acc0 = {0.f, 0.f, 0.f, 0.f};
    floatx4 acc1 = {0.f, 0.f, 0.f, 0.f};

    for (int kg0 = 0; kg0 < 576; kg0 += 32) {
        // ---- stage weight k-group [64co][32k] -> wlds ----
        if (use_wt) {
            *(half8*)&wlds[wco * CPAD + wk] =
                *(const half8*)&w2[wco * 576 + kg0 + wk];
        } else {
            const float4* ws4 = (const float4*)&w_dcn[wco * 576 + kg0 + wk];
            float4 f0 = ws4[0], f1 = ws4[1];
            half8 wv;
            wv[0] = (_Float16)f0.x; wv[1] = (_Float16)f0.y;
            wv[2] = (_Float16)f0.z; wv[3] = (_Float16)f0.w;
            wv[4] = (_Float16)f1.x; wv[5] = (_Float16)f1.y;
            wv[6] = (_Float16)f1.z; wv[7] = (_Float16)f1.w;
            *(half8*)&wlds[wco * CPAD + wk] = wv;
        }

        // ---- gather: thread owns k = kg0+kl, pixels p0..p0+3 ----
        int k   = kg0 + kl;
        int cin = k / 9;
        int tap = k - cin * 9;
        const float* xc = xb + (size_t)cin * (HDIM * WDIM);
#pragma unroll
        for (int i = 0; i < 4; ++i) {
            int px = p0 + i;
            unsigned m = gmeta[tap * GSTR + px];
            float4 w  = gwts[tap * GSTR + px];
            unsigned base = m & 0xfffu;
            unsigned dx   = (m >> 12) & 1u;
            unsigned dy64 = (m >> 7) & 64u;    // ((m>>13)&1)*64
            float v00 = xc[base];
            float v01 = xc[base + dx];
            float v10 = xc[base + dy64];
            float v11 = xc[base + dy64 + dx];
            float v = v00 * w.x + v01 * w.y + v10 * w.z + v11 * w.w;
            colsT[px * CPAD + kl] = (_Float16)v;
        }
        __syncthreads();

        // ---- MFMA: wave wid -> cout rows [16*wid, 16*wid+16), 2 px tiles --
        half8 afrag = *(const half8*)&wlds[(wid * 16 + (lane & 15)) * CPAD + (lane >> 4) * 8];
        half8 b0 = *(const half8*)&colsT[(lane & 15) * CPAD + (lane >> 4) * 8];
        half8 b1 = *(const half8*)&colsT[(16 + (lane & 15)) * CPAD + (lane >> 4) * 8];
        acc0 = __builtin_amdgcn_mfma_f32_16x16x32_f16(afrag, b0, acc0, 0, 0, 0);
        acc1 = __builtin_amdgcn_mfma_f32_16x16x32_f16(afrag, b1, acc1, 0, 0, 0);
        __syncthreads();
    }

    // ---------------- epilogue: bias + store -------------------------------
    const int col = lane & 15;
    const int r0  = (lane >> 4) * 4;
#pragma unroll
    for (int r = 0; r < 4; ++r) {
        int co = wid * 16 + r0 + r;
        float bias = b_dcn[co];
        size_t o = (((size_t)b * 64 + co) * HDIM + ho) * WDIM + half * PXB;
        out[o + col]      = acc0[r] + bias;
        out[o + 16 + col] = acc1[r] + bias;
    }
}

// ---------------------------------------------------------------------------
extern "C" void kernel_launch(void* const* d_in, const int* in_sizes, int n_in,
                              void* d_out, int out_size, void* d_ws, size_t ws_size,
                              hipStream_t stream) {
    const float* x     = (const float*)d_in[0];
    const float* w_off = (const float*)d_in[1];
    const float* b_off = (const float*)d_in[2];
    const float* w_dcn = (const float*)d_in[3];
    const float* b_dcn = (const float*)d_in[4];
    float* out = (float*)d_out;
    _Float16* w2 = (_Float16*)d_ws;

    int use_wt = (ws_size >= 576 * 64 * sizeof(_Float16)) ? 1 : 0;
    if (use_wt) {
        cvt_w<<<144, 256, 0, stream>>>(w_dcn, w2);
    }
    dcn_main<<<2048, 256, 0, stream>>>(x, w_off, b_off, w_dcn, w2, b_dcn, out,
                                       use_wt);
}

// Round 6
// 293.259 us; speedup vs baseline: 5.3120x; 3.4916x over previous
//
#include <hip/hip_runtime.h>
#include <hip/hip_fp16.h>

// DeformConv2d: B=16, Cin=64, Cout=64, H=W=64, K=3, stride=1, pad=1, dil=1
// Round 6: split pipeline. R3-R5's fused offset conv used per-lane weight
// addresses -> hoisted vector loads -> compiler spill storm (R5: VGPR=64,
// 1.7 GB scratch traffic). Split:
//   Kernel A (grid 1024): R2-style wave-uniform offset conv (scalar weight
//     loads) + geometry -> writes gather records (gmeta 4B, gwts 16B per
//     tap-px, 11.8 MB) to ws.
//   Kernel B (grid 2048, 32-px blocks): records -> LDS, gather, f16 MFMA.
//     Low register pressure => high occupancy with no spills.
// Fallback to fused path if ws too small.

#define HDIM 64
#define WDIM 64
#define KOFF 18
#define CPAD 40          // padded k-stride (halfs): 80B rows
#define PXB 32           // pixels per block (kernel B)
#define GSTR 33          // LDS geometry stride (records)

// ws layout
#define W2_BYTES   (576 * 64 * 2)                 // 73728
#define GMETA_OFF  (W2_BYTES)                     // 73728
#define GMETA_BYTES (16 * 64 * 9 * 64 * 4)        // 2359296
#define GWTS_OFF   (GMETA_OFF + GMETA_BYTES)      // 2433024 (16B aligned)
#define GWTS_BYTES (16 * 64 * 9 * 64 * 16)        // 9437184
#define WS_NEED    (GWTS_OFF + GWTS_BYTES)        // 11870208

typedef _Float16 half8 __attribute__((ext_vector_type(8)));
typedef float floatx4 __attribute__((ext_vector_type(4)));

// ---------------------------------------------------------------------------
__global__ void cvt_w(const float* __restrict__ w_dcn, _Float16* __restrict__ w2) {
    int e = blockIdx.x * 256 + threadIdx.x;
    if (e < 576 * 64) w2[e] = (_Float16)w_dcn[e];
}

// ---------------------------------------------------------------------------
// Kernel A: offset conv (wave-uniform scalar weight loads) + geometry records.
// One block per (b, ho); 64-px row; 4 waves x 16 cin.
__launch_bounds__(256)
__global__ void dcn_offsets(const float* __restrict__ x,
                            const float* __restrict__ w_off,
                            const float* __restrict__ b_off,
                            unsigned* __restrict__ gmeta_ws,
                            float4* __restrict__ gwts_ws) {
    const int bx = blockIdx.x;       // 0..1023
    const int b  = bx >> 6;
    const int ho = bx & 63;
    const int t  = threadIdx.x;
    const int p  = t & 63;
    const int g  = t >> 6;

    __shared__ float partial[4 * KOFF * 64];   // 18432 B
    __shared__ float offlds[KOFF * 64];        // 4608 B

    const float* xb = x + (size_t)b * 64 * (HDIM * WDIM);

    // offset conv: wave g handles cin [16g, 16g+16), weights via scalar loads
    {
        const int cinbase = __builtin_amdgcn_readfirstlane(g * 16);
        const float* wbase = w_off + cinbase * 9;
        float acc[KOFF];
#pragma unroll
        for (int i = 0; i < KOFF; ++i) acc[i] = 0.f;

        for (int ci = 0; ci < 16; ++ci) {
            const float* xc = xb + (size_t)(cinbase + ci) * (HDIM * WDIM);
#pragma unroll
            for (int ky = 0; ky < 3; ++ky) {
                int y = ho + ky - 1;
                bool yok = ((unsigned)y < (unsigned)HDIM);
#pragma unroll
                for (int kx = 0; kx < 3; ++kx) {
                    int xcol = p + kx - 1;
                    bool ok = yok && ((unsigned)xcol < (unsigned)WDIM);
                    float xv = ok ? xc[y * WDIM + xcol] : 0.f;
#pragma unroll
                    for (int co = 0; co < KOFF; ++co)
                        acc[co] += xv * wbase[co * 576 + ci * 9 + ky * 3 + kx];
                }
            }
        }
#pragma unroll
        for (int co = 0; co < KOFF; ++co)
            partial[(g * KOFF + co) * 64 + p] = acc[co];
        __syncthreads();
        for (int e = t; e < KOFF * 64; e += 256) {
            int co = e >> 6, pp = e & 63;
            float s = b_off[co];
#pragma unroll
            for (int q = 0; q < 4; ++q) s += partial[(q * KOFF + co) * 64 + pp];
            offlds[e] = s;
        }
        __syncthreads();
    }

    // geometry records for all 9 taps x 64 px of this row
    for (int e = t; e < 9 * 64; e += 256) {
        int tap = e / 64;                // 0..8
        int px  = e & 63;
        float offy = offlds[(2 * tap) * 64 + px];
        float offx = offlds[(2 * tap + 1) * 64 + px];
        float py  = offy + (float)(tap / 3) + (float)(ho - 1);
        float pxf = offx + (float)(tap % 3) + (float)(px - 1);
        float fy = floorf(py), fx = floorf(pxf);
        int y0 = (int)fy, x0 = (int)fx;
        float wy1 = py - fy, wx1 = pxf - fx;
        float wy0 = 1.f - wy1, wx0 = 1.f - wx1;
        bool y0ok = ((unsigned)y0 < (unsigned)HDIM);
        bool x0ok = ((unsigned)x0 < (unsigned)WDIM);
        bool y1ok = ((unsigned)(y0 + 1) < (unsigned)HDIM);
        bool x1ok = ((unsigned)(x0 + 1) < (unsigned)WDIM);
        float4 w;
        w.x = (y0ok && x0ok) ? wy0 * wx0 : 0.f;
        w.y = (y0ok && x1ok) ? wy0 * wx1 : 0.f;
        w.z = (y1ok && x0ok) ? wy1 * wx0 : 0.f;
        w.w = (y1ok && x1ok) ? wy1 * wx1 : 0.f;
        int yc0 = min(max(y0, 0), HDIM - 1);
        int xc0 = min(max(x0, 0), WDIM - 1);
        int yc1 = min(max(y0 + 1, 0), HDIM - 1);
        int xc1 = min(max(x0 + 1, 0), WDIM - 1);
        unsigned base = (unsigned)(yc0 * WDIM + xc0);
        unsigned dx   = (unsigned)(xc1 - xc0);
        unsigned dy   = (unsigned)(yc1 - yc0);
        size_t ridx = ((size_t)(b * 64 + ho) * 9 + tap) * 64 + px;
        gmeta_ws[ridx] = base | (dx << 12) | (dy << 13);
        gwts_ws[ridx]  = w;
    }
}

// ---------------------------------------------------------------------------
// Kernel B: gather + MFMA. One block per (b, ho, half-row of 32 px).
__launch_bounds__(256)
__global__ void dcn_gemm(const float* __restrict__ x,
                         const _Float16* __restrict__ w2,
                         const unsigned* __restrict__ gmeta_ws,
                         const float4* __restrict__ gwts_ws,
                         const float* __restrict__ b_dcn,
                         float* __restrict__ out) {
    const int bx   = blockIdx.x;        // 0..2047
    const int b    = bx >> 7;
    const int ho   = (bx >> 1) & 63;
    const int half = bx & 1;
    const int t    = threadIdx.x;
    const int lane = t & 63;
    const int wid  = t >> 6;

    __shared__ __align__(16) unsigned gmeta[9 * GSTR];      // 1188 B
    __shared__ __align__(16) float4   gwts[9 * GSTR];       // 4752 B
    __shared__ __align__(16) _Float16 colsT[PXB * CPAD];    // 2560 B
    __shared__ __align__(16) _Float16 wlds[64 * CPAD];      // 5120 B
    // ~13.6 KB

    const float* xb = x + (size_t)b * 64 * (HDIM * WDIM);

    // load this block's 288 geometry records (coalesced within taps)
    {
        const size_t rbase = ((size_t)(b * 64 + ho) * 9) * 64 + half * PXB;
        for (int e = t; e < 9 * PXB; e += 256) {
            int tap = e >> 5, px = e & 31;
            size_t ridx = rbase + (size_t)tap * 64 + px;
            gmeta[tap * GSTR + px] = gmeta_ws[ridx];
            gwts[tap * GSTR + px]  = gwts_ws[ridx];
        }
    }
    __syncthreads();

    const int kl  = t & 31;             // k within group (gather role)
    const int p0  = (t >> 5) * 4;       // 4-pixel strip (gather role)
    const int wco = t >> 2;             // staging role: cout
    const int wk  = (t & 3) * 8;        // staging role: k offset
    floatx4 acc0 = {0.f, 0.f, 0.f, 0.f};
    floatx4 acc1 = {0.f, 0.f, 0.f, 0.f};

    for (int kg0 = 0; kg0 < 576; kg0 += 32) {
        // stage weight k-group [64co][32k]
        *(half8*)&wlds[wco * CPAD + wk] = *(const half8*)&w2[wco * 576 + kg0 + wk];

        // gather: thread owns k = kg0+kl, pixels p0..p0+3
        int k   = kg0 + kl;
        int cin = k / 9;
        int tap = k - cin * 9;
        const float* xc = xb + (size_t)cin * (HDIM * WDIM);
#pragma unroll
        for (int i = 0; i < 4; ++i) {
            int px = p0 + i;
            unsigned m = gmeta[tap * GSTR + px];
            float4 w  = gwts[tap * GSTR + px];
            unsigned base = m & 0xfffu;
            unsigned dx   = (m >> 12) & 1u;
            unsigned dy64 = (m >> 7) & 64u;
            float v00 = xc[base];
            float v01 = xc[base + dx];
            float v10 = xc[base + dy64];
            float v11 = xc[base + dy64 + dx];
            float v = v00 * w.x + v01 * w.y + v10 * w.z + v11 * w.w;
            colsT[px * CPAD + kl] = (_Float16)v;
        }
        __syncthreads();

        half8 afrag = *(const half8*)&wlds[(wid * 16 + (lane & 15)) * CPAD + (lane >> 4) * 8];
        half8 b0 = *(const half8*)&colsT[(lane & 15) * CPAD + (lane >> 4) * 8];
        half8 b1 = *(const half8*)&colsT[(16 + (lane & 15)) * CPAD + (lane >> 4) * 8];
        acc0 = __builtin_amdgcn_mfma_f32_16x16x32_f16(afrag, b0, acc0, 0, 0, 0);
        acc1 = __builtin_amdgcn_mfma_f32_16x16x32_f16(afrag, b1, acc1, 0, 0, 0);
        __syncthreads();
    }

    const int col = lane & 15;
    const int r0  = (lane >> 4) * 4;
#pragma unroll
    for (int r = 0; r < 4; ++r) {
        int co = wid * 16 + r0 + r;
        float bias = b_dcn[co];
        size_t o = (((size_t)b * 64 + co) * HDIM + ho) * WDIM + half * PXB;
        out[o + col]      = acc0[r] + bias;
        out[o + 16 + col] = acc1[r] + bias;
    }
}

// ---------------------------------------------------------------------------
// Fused fallback (R5 path) for small ws. Only used when ws_size < WS_NEED.
__launch_bounds__(256, 4)
__global__ void dcn_fused(const float* __restrict__ x,
                          const float* __restrict__ w_off,
                          const float* __restrict__ b_off,
                          const float* __restrict__ w_dcn,
                          const _Float16* __restrict__ w2,
                          const float* __restrict__ b_dcn,
                          float* __restrict__ out,
                          int use_wt) {
    const int bx   = blockIdx.x;
    const int b    = bx >> 7;
    const int ho   = (bx >> 1) & 63;
    const int half = bx & 1;
    const int t    = threadIdx.x;
    const int lane = t & 63;
    const int wid  = t >> 6;

    __shared__ __align__(16) float    offlds[KOFF * PXB];
    __shared__ __align__(16) unsigned gmeta[9 * GSTR];
    __shared__ __align__(16) float4   gwts[9 * GSTR];
    __shared__ __align__(16) _Float16 colsT[PXB * CPAD];
    __shared__ __align__(16) _Float16 wlds[64 * CPAD];

    const float* xb = x + (size_t)b * 64 * (HDIM * WDIM);

    {
        const int px = t >> 3;
        const int c8 = t & 7;
        const int gx = half * PXB + px;
        const int cb = c8 * 8;
        float acc[KOFF];
#pragma unroll
        for (int i = 0; i < KOFF; ++i) acc[i] = 0.f;
        for (int ci = 0; ci < 8; ++ci) {
            const float* xc = xb + (size_t)(cb + ci) * (HDIM * WDIM);
#pragma unroll
            for (int ky = 0; ky < 3; ++ky) {
                int y = ho + ky - 1;
                bool yok = ((unsigned)y < (unsigned)HDIM);
#pragma unroll
                for (int kx = 0; kx < 3; ++kx) {
                    int xcol = gx + kx - 1;
                    bool ok = yok && ((unsigned)xcol < (unsigned)WDIM);
                    float xv = ok ? xc[y * WDIM + xcol] : 0.f;
#pragma unroll
                    for (int co = 0; co < KOFF; ++co)
                        acc[co] += xv * w_off[co * 576 + (cb + ci) * 9 + ky * 3 + kx];
                }
            }
        }
#pragma unroll
        for (int co = 0; co < KOFF; ++co) {
            float v = acc[co];
            v += __shfl_xor(v, 1);
            v += __shfl_xor(v, 2);
            v += __shfl_xor(v, 4);
            if (c8 == 0) offlds[co * PXB + px] = v + b_off[co];
        }
    }
    __syncthreads();

    for (int e = t; e < 9 * PXB; e += 256) {
        int tap = e >> 5;
        int px  = e & 31;
        float offy = offlds[(2 * tap) * PXB + px];
        float offx = offlds[(2 * tap + 1) * PXB + px];
        float py  = offy + (float)(tap / 3) + (float)(ho - 1);
        float pxf = offx + (float)(tap % 3) + (float)(half * PXB + px - 1);
        float fy = floorf(py), fx = floorf(pxf);
        int y0 = (int)fy, x0 = (int)fx;
        float wy1 = py - fy, wx1 = pxf - fx;
        float wy0 = 1.f - wy1, wx0 = 1.f - wx1;
        bool y0ok = ((unsigned)y0 < (unsigned)HDIM);
        bool x0ok = ((unsigned)x0 < (unsigned)WDIM);
        bool y1ok = ((unsigned)(y0 + 1) < (unsigned)HDIM);
        bool x1ok = ((unsigned)(x0 + 1) < (unsigned)WDIM);
        float4 w;
        w.x = (y0ok && x0ok) ? wy0 * wx0 : 0.f;
        w.y = (y0ok && x1ok) ? wy0 * wx1 : 0.f;
        w.z = (y1ok && x0ok) ? wy1 * wx0 : 0.f;
        w.w = (y1ok && x1ok) ? wy1 * wx1 : 0.f;
        int yc0 = min(max(y0, 0), HDIM - 1);
        int xc0 = min(max(x0, 0), WDIM - 1);
        int yc1 = min(max(y0 + 1, 0), HDIM - 1);
        int xc1 = min(max(x0 + 1, 0), WDIM - 1);
        unsigned base = (unsigned)(yc0 * WDIM + xc0);
        unsigned dx   = (unsigned)(xc1 - xc0);
        unsigned dy   = (unsigned)(yc1 - yc0);
        gmeta[tap * GSTR + px] = base | (dx << 12) | (dy << 13);
        gwts[tap * GSTR + px]  = w;
    }
    __syncthreads();

    const int kl = t & 31;
    const int p0 = (t >> 5) * 4;
    const int wco = t >> 2;
    const int wk  = (t & 3) * 8;
    floatx4 acc0 = {0.f, 0.f, 0.f, 0.f};
    floatx4 acc1 = {0.f, 0.f, 0.f, 0.f};

    for (int kg0 = 0; kg0 < 576; kg0 += 32) {
        if (use_wt) {
            *(half8*)&wlds[wco * CPAD + wk] =
                *(const half8*)&w2[wco * 576 + kg0 + wk];
        } else {
            const float4* ws4 = (const float4*)&w_dcn[wco * 576 + kg0 + wk];
            float4 f0 = ws4[0], f1 = ws4[1];
            half8 wv;
            wv[0] = (_Float16)f0.x; wv[1] = (_Float16)f0.y;
            wv[2] = (_Float16)f0.z; wv[3] = (_Float16)f0.w;
            wv[4] = (_Float16)f1.x; wv[5] = (_Float16)f1.y;
            wv[6] = (_Float16)f1.z; wv[7] = (_Float16)f1.w;
            *(half8*)&wlds[wco * CPAD + wk] = wv;
        }
        int k   = kg0 + kl;
        int cin = k / 9;
        int tap = k - cin * 9;
        const float* xc = xb + (size_t)cin * (HDIM * WDIM);
#pragma unroll
        for (int i = 0; i < 4; ++i) {
            int px = p0 + i;
            unsigned m = gmeta[tap * GSTR + px];
            float4 w  = gwts[tap * GSTR + px];
            unsigned base = m & 0xfffu;
            unsigned dx   = (m >> 12) & 1u;
            unsigned dy64 = (m >> 7) & 64u;
            float v00 = xc[base];
            float v01 = xc[base + dx];
            float v10 = xc[base + dy64];
            float v11 = xc[base + dy64 + dx];
            float v = v00 * w.x + v01 * w.y + v10 * w.z + v11 * w.w;
            colsT[px * CPAD + kl] = (_Float16)v;
        }
        __syncthreads();

        half8 afrag = *(const half8*)&wlds[(wid * 16 + (lane & 15)) * CPAD + (lane >> 4) * 8];
        half8 b0 = *(const half8*)&colsT[(lane & 15) * CPAD + (lane >> 4) * 8];
        half8 b1 = *(const half8*)&colsT[(16 + (lane & 15)) * CPAD + (lane >> 4) * 8];
        acc0 = __builtin_amdgcn_mfma_f32_16x16x32_f16(afrag, b0, acc0, 0, 0, 0);
        acc1 = __builtin_amdgcn_mfma_f32_16x16x32_f16(afrag, b1, acc1, 0, 0, 0);
        __syncthreads();
    }

    const int col = lane & 15;
    const int r0  = (lane >> 4) * 4;
#pragma unroll
    for (int r = 0; r < 4; ++r) {
        int co = wid * 16 + r0 + r;
        float bias = b_dcn[co];
        size_t o = (((size_t)b * 64 + co) * HDIM + ho) * WDIM + half * PXB;
        out[o + col]      = acc0[r] + bias;
        out[o + 16 + col] = acc1[r] + bias;
    }
}

// ---------------------------------------------------------------------------
extern "C" void kernel_launch(void* const* d_in, const int* in_sizes, int n_in,
                              void* d_out, int out_size, void* d_ws, size_t ws_size,
                              hipStream_t stream) {
    const float* x     = (const float*)d_in[0];
    const float* w_off = (const float*)d_in[1];
    const float* b_off = (const float*)d_in[2];
    const float* w_dcn = (const float*)d_in[3];
    const float* b_dcn = (const float*)d_in[4];
    float* out = (float*)d_out;

    char* ws = (char*)d_ws;
    _Float16* w2        = (_Float16*)ws;
    unsigned* gmeta_ws  = (unsigned*)(ws + GMETA_OFF);
    float4*   gwts_ws   = (float4*)(ws + GWTS_OFF);

    if (ws_size >= (size_t)WS_NEED) {
        cvt_w<<<144, 256, 0, stream>>>(w_dcn, w2);
        dcn_offsets<<<1024, 256, 0, stream>>>(x, w_off, b_off, gmeta_ws, gwts_ws);
        dcn_gemm<<<2048, 256, 0, stream>>>(x, w2, gmeta_ws, gwts_ws, b_dcn, out);
    } else if (ws_size >= (size_t)W2_BYTES) {
        cvt_w<<<144, 256, 0, stream>>>(w_dcn, w2);
        dcn_fused<<<2048, 256, 0, stream>>>(x, w_off, b_off, w_dcn, w2, b_dcn,
                                            out, 1);
    } else {
        dcn_fused<<<2048, 256, 0, stream>>>(x, w_off, b_off, w_dcn, w2, b_dcn,
                                            out, 0);
    }
}

// Round 7
// 218.416 us; speedup vs baseline: 7.1322x; 1.3427x over previous
//
#include <hip/hip_runtime.h>
#include <hip/hip_fp16.h>

// DeformConv2d: B=16, Cin=64, Cout=64, H=W=64, K=3, stride=1, pad=1, dil=1
// Round 7: fix the TA address-throughput wall found in R6.
//  Kernel B gather role transposed: lanes = consecutive pixels, (cin,tap)
//    wave-group-uniform -> coalesced gather (was 64 cache lines/instr).
//    Geometry record = 16B {meta, half2 w00w01, half2 w10w11} -> 1 ds_read.
//  Kernel A: w_off staged to LDS [cin][tap][co+pad], broadcast ds_reads
//    replace 2592 serializing scalar loads.

#define HDIM 64
#define WDIM 64
#define KOFF 18
#define CPAD 40          // padded k-stride (halfs): 80B rows
#define PXB 32           // pixels per block (kernel B)
#define GSTR 33          // LDS geometry record stride
#define WOP 20           // A: co-stride (18 + 2 pad) in wofflds

// ws layout
#define W2_BYTES   (576 * 64 * 2)                 // 73728
#define GREC_OFF   (W2_BYTES)                     // 16B aligned
#define GREC_BYTES (16 * 64 * 9 * 64 * 16)        // 9437184
#define WS_NEED    (GREC_OFF + GREC_BYTES)

typedef _Float16 half8 __attribute__((ext_vector_type(8)));
typedef _Float16 half4 __attribute__((ext_vector_type(4)));
typedef float floatx4 __attribute__((ext_vector_type(4)));

// ---------------------------------------------------------------------------
__global__ void cvt_w(const float* __restrict__ w_dcn, _Float16* __restrict__ w2) {
    int e = blockIdx.x * 256 + threadIdx.x;
    if (e < 576 * 64) w2[e] = (_Float16)w_dcn[e];
}

// ---------------------------------------------------------------------------
// Kernel A: offset conv + geometry records (one block per (b,ho) row).
__launch_bounds__(256)
__global__ void dcn_offsets(const float* __restrict__ x,
                            const float* __restrict__ w_off,
                            const float* __restrict__ b_off,
                            uint4* __restrict__ grecs) {
    const int bx = blockIdx.x;       // 0..1023
    const int b  = bx >> 6;
    const int ho = bx & 63;
    const int t  = threadIdx.x;
    const int p  = t & 63;
    const int g  = t >> 6;

    __shared__ float wofflds[64 * 9 * WOP];    // 46080 B: [cin][tap][co pad20]
    __shared__ float partial[4 * KOFF * 64];   // 18432 B
    __shared__ float offlds[KOFF * 64];        // 4608 B

    const float* xb = x + (size_t)b * 64 * (HDIM * WDIM);

    // stage w_off [co][cin][tap] -> LDS [cin][tap][co]
    for (int e = t; e < 64 * 9 * KOFF; e += 256) {
        int ci  = e / 162;
        int rem = e - ci * 162;
        int co  = rem / 9;
        int tap = rem - co * 9;
        wofflds[(ci * 9 + tap) * WOP + co] = w_off[co * 576 + ci * 9 + tap];
    }
    __syncthreads();

    // offset conv: wave g handles cin [16g,16g+16); weights via LDS broadcast
    {
        const int cinbase = g * 16;
        float acc[KOFF];
#pragma unroll
        for (int i = 0; i < KOFF; ++i) acc[i] = 0.f;

        for (int ci = 0; ci < 16; ++ci) {
            const int cin = cinbase + ci;
            const float* xc = xb + (size_t)cin * (HDIM * WDIM);
            float xv[9];
#pragma unroll
            for (int ky = 0; ky < 3; ++ky) {
                int y = ho + ky - 1;
                bool yok = ((unsigned)y < (unsigned)HDIM);
#pragma unroll
                for (int kx = 0; kx < 3; ++kx) {
                    int xcol = p + kx - 1;
                    bool ok = yok && ((unsigned)xcol < (unsigned)WDIM);
                    xv[ky * 3 + kx] = ok ? xc[y * WDIM + xcol] : 0.f;
                }
            }
#pragma unroll
            for (int tap = 0; tap < 9; ++tap) {
                const float* wp = &wofflds[(cin * 9 + tap) * WOP];
#pragma unroll
                for (int co = 0; co < KOFF; ++co)
                    acc[co] += xv[tap] * wp[co];
            }
        }
#pragma unroll
        for (int co = 0; co < KOFF; ++co)
            partial[(g * KOFF + co) * 64 + p] = acc[co];
        __syncthreads();
        for (int e = t; e < KOFF * 64; e += 256) {
            int co = e >> 6, pp = e & 63;
            float s = b_off[co];
#pragma unroll
            for (int q = 0; q < 4; ++q) s += partial[(q * KOFF + co) * 64 + pp];
            offlds[e] = s;
        }
        __syncthreads();
    }

    // geometry records: 9 taps x 64 px -> 16B each
    for (int e = t; e < 9 * 64; e += 256) {
        int tap = e >> 6;
        int px  = e & 63;
        float offy = offlds[(2 * tap) * 64 + px];
        float offx = offlds[(2 * tap + 1) * 64 + px];
        float py  = offy + (float)(tap / 3) + (float)(ho - 1);
        float pxf = offx + (float)(tap % 3) + (float)(px - 1);
        float fy = floorf(py), fx = floorf(pxf);
        int y0 = (int)fy, x0 = (int)fx;
        float wy1 = py - fy, wx1 = pxf - fx;
        float wy0 = 1.f - wy1, wx0 = 1.f - wx1;
        bool y0ok = ((unsigned)y0 < (unsigned)HDIM);
        bool x0ok = ((unsigned)x0 < (unsigned)WDIM);
        bool y1ok = ((unsigned)(y0 + 1) < (unsigned)HDIM);
        bool x1ok = ((unsigned)(x0 + 1) < (unsigned)WDIM);
        float w00 = (y0ok && x0ok) ? wy0 * wx0 : 0.f;
        float w01 = (y0ok && x1ok) ? wy0 * wx1 : 0.f;
        float w10 = (y1ok && x0ok) ? wy1 * wx0 : 0.f;
        float w11 = (y1ok && x1ok) ? wy1 * wx1 : 0.f;
        int yc0 = min(max(y0, 0), HDIM - 1);
        int xc0 = min(max(x0, 0), WDIM - 1);
        int yc1 = min(max(y0 + 1, 0), HDIM - 1);
        int xc1 = min(max(x0 + 1, 0), WDIM - 1);
        unsigned base = (unsigned)(yc0 * WDIM + xc0);
        unsigned dx   = (unsigned)(xc1 - xc0);
        unsigned dy   = (unsigned)(yc1 - yc0);
        union { __half2 h; unsigned u; } c0, c1;
        c0.h = __floats2half2_rn(w00, w01);
        c1.h = __floats2half2_rn(w10, w11);
        uint4 rec;
        rec.x = base | (dx << 12) | (dy << 13);
        rec.y = c0.u;
        rec.z = c1.u;
        rec.w = 0u;
        grecs[((size_t)(b * 64 + ho) * 9 + tap) * 64 + px] = rec;
    }
}

// ---------------------------------------------------------------------------
// Kernel B: gather + MFMA. One block per (b, ho, 32-px half-row).
// Gather role: gi = t>>5 (8 groups), px = t&31 -> lanes are consecutive
// pixels with group-uniform (cin,tap) -> coalesced loads.
__launch_bounds__(256)
__global__ void dcn_gemm(const float* __restrict__ x,
                         const _Float16* __restrict__ w2,
                         const uint4* __restrict__ grecs,
                         const float* __restrict__ b_dcn,
                         float* __restrict__ out) {
    const int bx   = blockIdx.x;        // 0..2047
    const int b    = bx >> 7;
    const int ho   = (bx >> 1) & 63;
    const int half = bx & 1;
    const int t    = threadIdx.x;
    const int lane = t & 63;
    const int wid  = t >> 6;

    __shared__ __align__(16) uint4    grec[9 * GSTR];       // 4752 B
    __shared__ __align__(16) _Float16 colsT[PXB * CPAD];    // 2560 B
    __shared__ __align__(16) _Float16 wlds[64 * CPAD];      // 5120 B
    // ~12.2 KB

    const float* xb = x + (size_t)b * 64 * (HDIM * WDIM);

    // load this block's 288 records (coalesced)
    {
        const size_t rbase = ((size_t)(b * 64 + ho) * 9) * 64 + half * PXB;
        for (int e = t; e < 9 * PXB; e += 256) {
            int tap = e >> 5, px = e & 31;
            grec[tap * GSTR + px] = grecs[rbase + (size_t)tap * 64 + px];
        }
    }
    __syncthreads();

    const int gi  = t >> 5;             // gather group 0..7
    const int px  = t & 31;             // pixel (consecutive within group)
    const int wco = t >> 2;             // staging role: cout
    const int wk  = (t & 3) * 8;        // staging role: k offset
    floatx4 acc0 = {0.f, 0.f, 0.f, 0.f};
    floatx4 acc1 = {0.f, 0.f, 0.f, 0.f};

    for (int kg0 = 0; kg0 < 576; kg0 += 32) {
        // stage weight k-group [64co][32k]
        *(half8*)&wlds[wco * CPAD + wk] = *(const half8*)&w2[wco * 576 + kg0 + wk];

        // gather: thread owns contiguous k_local = gi*4 .. gi*4+3, pixel px
        half4 vb;
#pragma unroll
        for (int j = 0; j < 4; ++j) {
            int k   = kg0 + gi * 4 + j;
            int cin = k / 9;
            int tap = k - cin * 9;
            const float* xc = xb + (size_t)cin * (HDIM * WDIM);
            uint4 r = grec[tap * GSTR + px];
            unsigned base = r.x & 0xfffu;
            unsigned dx   = (r.x >> 12) & 1u;
            unsigned dy64 = (r.x >> 7) & 64u;
            union { unsigned u; __half2 h; } c0, c1;
            c0.u = r.y; c1.u = r.z;
            float v00 = xc[base];
            float v01 = xc[base + dx];
            float v10 = xc[base + dy64];
            float v11 = xc[base + dy64 + dx];
            float v = v00 * (float)c0.h.x + v01 * (float)c0.h.y
                    + v10 * (float)c1.h.x + v11 * (float)c1.h.y;
            vb[j] = (_Float16)v;
        }
        *(half4*)&colsT[px * CPAD + gi * 4] = vb;   // 8B, aligned
        __syncthreads();

        half8 afrag = *(const half8*)&wlds[(wid * 16 + (lane & 15)) * CPAD + (lane >> 4) * 8];
        half8 b0 = *(const half8*)&colsT[(lane & 15) * CPAD + (lane >> 4) * 8];
        half8 b1 = *(const half8*)&colsT[(16 + (lane & 15)) * CPAD + (lane >> 4) * 8];
        acc0 = __builtin_amdgcn_mfma_f32_16x16x32_f16(afrag, b0, acc0, 0, 0, 0);
        acc1 = __builtin_amdgcn_mfma_f32_16x16x32_f16(afrag, b1, acc1, 0, 0, 0);
        __syncthreads();
    }

    const int col = lane & 15;
    const int r0  = (lane >> 4) * 4;
#pragma unroll
    for (int r = 0; r < 4; ++r) {
        int co = wid * 16 + r0 + r;
        float bias = b_dcn[co];
        size_t o = (((size_t)b * 64 + co) * HDIM + ho) * WDIM + half * PXB;
        out[o + col]      = acc0[r] + bias;
        out[o + 16 + col] = acc1[r] + bias;
    }
}

// ---------------------------------------------------------------------------
// Fused fallback (R6 path) used only when ws is too small.
__launch_bounds__(256, 4)
__global__ void dcn_fused(const float* __restrict__ x,
                          const float* __restrict__ w_off,
                          const float* __restrict__ b_off,
                          const float* __restrict__ w_dcn,
                          const float* __restrict__ b_dcn,
                          float* __restrict__ out) {
    const int bx   = blockIdx.x;
    const int b    = bx >> 7;
    const int ho   = (bx >> 1) & 63;
    const int half = bx & 1;
    const int t    = threadIdx.x;
    const int lane = t & 63;
    const int wid  = t >> 6;

    __shared__ __align__(16) float    offlds[KOFF * PXB];
    __shared__ __align__(16) uint4    grec[9 * GSTR];
    __shared__ __align__(16) _Float16 colsT[PXB * CPAD];
    __shared__ __align__(16) _Float16 wlds[64 * CPAD];

    const float* xb = x + (size_t)b * 64 * (HDIM * WDIM);

    {
        const int px = t >> 3;
        const int c8 = t & 7;
        const int gx = half * PXB + px;
        const int cb = c8 * 8;
        float acc[KOFF];
#pragma unroll
        for (int i = 0; i < KOFF; ++i) acc[i] = 0.f;
        for (int ci = 0; ci < 8; ++ci) {
            const float* xc = xb + (size_t)(cb + ci) * (HDIM * WDIM);
#pragma unroll
            for (int ky = 0; ky < 3; ++ky) {
                int y = ho + ky - 1;
                bool yok = ((unsigned)y < (unsigned)HDIM);
#pragma unroll
                for (int kx = 0; kx < 3; ++kx) {
                    int xcol = gx + kx - 1;
                    bool ok = yok && ((unsigned)xcol < (unsigned)WDIM);
                    float xv = ok ? xc[y * WDIM + xcol] : 0.f;
#pragma unroll
                    for (int co = 0; co < KOFF; ++co)
                        acc[co] += xv * w_off[co * 576 + (cb + ci) * 9 + ky * 3 + kx];
                }
            }
        }
#pragma unroll
        for (int co = 0; co < KOFF; ++co) {
            float v = acc[co];
            v += __shfl_xor(v, 1);
            v += __shfl_xor(v, 2);
            v += __shfl_xor(v, 4);
            if (c8 == 0) offlds[co * PXB + px] = v + b_off[co];
        }
    }
    __syncthreads();

    for (int e = t; e < 9 * PXB; e += 256) {
        int tap = e >> 5;
        int px  = e & 31;
        float offy = offlds[(2 * tap) * PXB + px];
        float offx = offlds[(2 * tap + 1) * PXB + px];
        float py  = offy + (float)(tap / 3) + (float)(ho - 1);
        float pxf = offx + (float)(tap % 3) + (float)(half * PXB + px - 1);
        float fy = floorf(py), fx = floorf(pxf);
        int y0 = (int)fy, x0 = (int)fx;
        float wy1 = py - fy, wx1 = pxf - fx;
        float wy0 = 1.f - wy1, wx0 = 1.f - wx1;
        bool y0ok = ((unsigned)y0 < (unsigned)HDIM);
        bool x0ok = ((unsigned)x0 < (unsigned)WDIM);
        bool y1ok = ((unsigned)(y0 + 1) < (unsigned)HDIM);
        bool x1ok = ((unsigned)(x0 + 1) < (unsigned)WDIM);
        float w00 = (y0ok && x0ok) ? wy0 * wx0 : 0.f;
        float w01 = (y0ok && x1ok) ? wy0 * wx1 : 0.f;
        float w10 = (y1ok && x0ok) ? wy1 * wx0 : 0.f;
        float w11 = (y1ok && x1ok) ? wy1 * wx1 : 0.f;
        int yc0 = min(max(y0, 0), HDIM - 1);
        int xc0 = min(max(x0, 0), WDIM - 1);
        int yc1 = min(max(y0 + 1, 0), HDIM - 1);
        int xc1 = min(max(x0 + 1, 0), WDIM - 1);
        union { __half2 h; unsigned u; } c0, c1;
        c0.h = __floats2half2_rn(w00, w01);
        c1.h = __floats2half2_rn(w10, w11);
        uint4 rec;
        rec.x = (unsigned)(yc0 * WDIM + xc0) | ((unsigned)(xc1 - xc0) << 12)
              | ((unsigned)(yc1 - yc0) << 13);
        rec.y = c0.u;
        rec.z = c1.u;
        rec.w = 0u;
        grec[tap * GSTR + px] = rec;
    }
    __syncthreads();

    const int gi = t >> 5;
    const int px = t & 31;
    const int wco = t >> 2;
    const int wk  = (t & 3) * 8;
    floatx4 acc0 = {0.f, 0.f, 0.f, 0.f};
    floatx4 acc1 = {0.f, 0.f, 0.f, 0.f};

    for (int kg0 = 0; kg0 < 576; kg0 += 32) {
        {
            const float4* ws4 = (const float4*)&w_dcn[wco * 576 + kg0 + wk];
            float4 f0 = ws4[0], f1 = ws4[1];
            half8 wv;
            wv[0] = (_Float16)f0.x; wv[1] = (_Float16)f0.y;
            wv[2] = (_Float16)f0.z; wv[3] = (_Float16)f0.w;
            wv[4] = (_Float16)f1.x; wv[5] = (_Float16)f1.y;
            wv[6] = (_Float16)f1.z; wv[7] = (_Float16)f1.w;
            *(half8*)&wlds[wco * CPAD + wk] = wv;
        }
        half4 vb;
#pragma unroll
        for (int j = 0; j < 4; ++j) {
            int k   = kg0 + gi * 4 + j;
            int cin = k / 9;
            int tap = k - cin * 9;
            const float* xc = xb + (size_t)cin * (HDIM * WDIM);
            uint4 r = grec[tap * GSTR + px];
            unsigned base = r.x & 0xfffu;
            unsigned dx   = (r.x >> 12) & 1u;
            unsigned dy64 = (r.x >> 7) & 64u;
            union { unsigned u; __half2 h; } c0, c1;
            c0.u = r.y; c1.u = r.z;
            float v00 = xc[base];
            float v01 = xc[base + dx];
            float v10 = xc[base + dy64];
            float v11 = xc[base + dy64 + dx];
            float v = v00 * (float)c0.h.x + v01 * (float)c0.h.y
                    + v10 * (float)c1.h.x + v11 * (float)c1.h.y;
            vb[j] = (_Float16)v;
        }
        *(half4*)&colsT[px * CPAD + gi * 4] = vb;
        __syncthreads();

        half8 afrag = *(const half8*)&wlds[(wid * 16 + (lane & 15)) * CPAD + (lane >> 4) * 8];
        half8 b0 = *(const half8*)&colsT[(lane & 15) * CPAD + (lane >> 4) * 8];
        half8 b1 = *(const half8*)&colsT[(16 + (lane & 15)) * CPAD + (lane >> 4) * 8];
        acc0 = __builtin_amdgcn_mfma_f32_16x16x32_f16(afrag, b0, acc0, 0, 0, 0);
        acc1 = __builtin_amdgcn_mfma_f32_16x16x32_f16(afrag, b1, acc1, 0, 0, 0);
        __syncthreads();
    }

    const int col = lane & 15;
    const int r0  = (lane >> 4) * 4;
#pragma unroll
    for (int r = 0; r < 4; ++r) {
        int co = wid * 16 + r0 + r;
        float bias = b_dcn[co];
        size_t o = (((size_t)b * 64 + co) * HDIM + ho) * WDIM + half * PXB;
        out[o + col]      = acc0[r] + bias;
        out[o + 16 + col] = acc1[r] + bias;
    }
}

// ---------------------------------------------------------------------------
extern "C" void kernel_launch(void* const* d_in, const int* in_sizes, int n_in,
                              void* d_out, int out_size, void* d_ws, size_t ws_size,
                              hipStream_t stream) {
    const float* x     = (const float*)d_in[0];
    const float* w_off = (const float*)d_in[1];
    const float* b_off = (const float*)d_in[2];
    const float* w_dcn = (const float*)d_in[3];
    const float* b_dcn = (const float*)d_in[4];
    float* out = (float*)d_out;

    char* ws = (char*)d_ws;
    _Float16* w2   = (_Float16*)ws;
    uint4*    grecs = (uint4*)(ws + GREC_OFF);

    if (ws_size >= (size_t)WS_NEED) {
        cvt_w<<<144, 256, 0, stream>>>(w_dcn, w2);
        dcn_offsets<<<1024, 256, 0, stream>>>(x, w_off, b_off, grecs);
        dcn_gemm<<<2048, 256, 0, stream>>>(x, w2, grecs, b_dcn, out);
    } else {
        dcn_fused<<<2048, 256, 0, stream>>>(x, w_off, b_off, w_dcn, b_dcn, out);
    }
}